// Round 12
// baseline (3222.902 us; speedup 1.0000x reference)
//
#include <hip/hip_runtime.h>
#include <stdint.h>

// ---------------------------------------------------------------------------
// HMM forward: B=256, T=512, Q=1027, ALPHA=26.
// R12 = R7 (2152us, best) + two surgical fixes:
//  (i)  Coalesced exchange stores: producer wave transposes its 16x16 (m x q)
//       tile in a small LDS buffer (4x ds_write_b32 + 1x ds_read_b128), packs
//       bf16, and stores its whole 512B image contribution with ONE
//       global_store_dwordx2 (was 4x scattered 2B global_store_short ->
//       dozens of partial-sector MALL transactions serializing the drain and
//       amplifying WRITE_SIZE). Image layout byte-identical to R7.
//  (ii) Counted first poll: w0 pre-issues its poll load in POST right after
//       the flag store, BEFORE the out-stores; first WAIT uses vmcnt(4) so
//       in-order retirement gives the poll value without waiting the HBM
//       out-store acks. (t=1 uses vmcnt(0): no prior out-stores.)
// Everything else byte-identical to R7: 16 clusters x 16 WGs (256 thr, 4
// waves); wave (j,w) owns tile tg=4j+w; WG15 owns cols 1024..1026 (tile64,
// kc%4 split); 2-parity fragment-layout exchange; reg-direct MFMA + accx
// reduce; f32 Sp side-channel; single-drain POST; w0-only poll with sleep.
// All cross-WG traffic sc0 sc1 (device scope, placement-independent).
// ---------------------------------------------------------------------------

#define Q     1027
#define TT    512
#define ALPH  26
#define KCH   33              // k-chunks of 32 (K padded to 1056)
#define NTILE 65
#define NCHK  (KCH*64)        // 2112 chunks
#define GIMG  (NCHK*16)       // 33792 B per (cluster,parity) image
#define NCL   16
#define WPC   16
#define MB    16

typedef short  short8  __attribute__((ext_vector_type(8)));
typedef float  floatx4 __attribute__((ext_vector_type(4)));
typedef int    intx4   __attribute__((ext_vector_type(4)));
typedef int    intx2   __attribute__((ext_vector_type(2)));

static constexpr size_t al512(size_t x) { return (x + 511) & ~size_t(511); }
static constexpr size_t OFF_APACK = 0;
static constexpr size_t SZ_APACK  = (size_t)NTILE * KCH * 64 * 16;   // 2,196,480
static constexpr size_t OFF_BSOFT = al512(OFF_APACK + SZ_APACK);
static constexpr size_t SZ_BSOFT  = (size_t)Q * ALPH * 4;
static constexpr size_t OFF_INIT  = al512(OFF_BSOFT + SZ_BSOFT);
static constexpr size_t OFF_AMAX  = al512(OFF_INIT + Q * 4);
static constexpr size_t OFF_AINV  = al512(OFF_AMAX + Q * 4);
static constexpr size_t OFF_GEX   = al512(OFF_AINV + Q * 4);
static constexpr size_t SZ_GEX    = (size_t)NCL * 2 * GIMG;          // 1,081,344
static constexpr size_t OFF_SP    = al512(OFF_GEX + SZ_GEX);         // [c][p][tg 64][m 16] f32
static constexpr size_t SZ_SP     = (size_t)NCL * 2 * 64 * MB * 4;   // 131,072
static constexpr size_t OFF_FLAGS = al512(OFF_SP + SZ_SP);           // [c][tg 64] int
static constexpr size_t SZ_FLAGS  = (size_t)NCL * 64 * 4;            // 4,096
static constexpr size_t WS_NEED   = OFF_FLAGS + SZ_FLAGS;            // ~3.38 MB
static constexpr size_t FWDSZ     = (size_t)256 * TT * Q;

__device__ __forceinline__ uint32_t f2bf(float f) {
  uint32_t u = __float_as_uint(f);
  return (u + 0x7fffu + ((u >> 16) & 1u)) >> 16;   // RNE
}

// ------------------------- prep kernels ------------------------------------

__global__ void k_zero(char* __restrict__ ws) {
  const size_t n = (WS_NEED - OFF_GEX) / 16;
  intx4* p = (intx4*)(ws + OFF_GEX);
  for (size_t i = (size_t)blockIdx.x * 256 + threadIdx.x; i < n; i += (size_t)80 * 256)
    p[i] = intx4{0, 0, 0, 0};
}

__global__ void k_astats(const float* __restrict__ A, char* __restrict__ ws) {
  const int r = blockIdx.x, tid = threadIdx.x;
  const float* row = A + (size_t)r * Q;
  __shared__ float red[4], red2[4];
  float mx = -3.0e38f;
  for (int i = tid; i < Q; i += 256) mx = fmaxf(mx, row[i]);
#pragma unroll
  for (int d = 1; d < 64; d <<= 1) mx = fmaxf(mx, __shfl_xor(mx, d));
  if ((tid & 63) == 0) red[tid >> 6] = mx;
  __syncthreads();
  mx = fmaxf(fmaxf(red[0], red[1]), fmaxf(red[2], red[3]));
  float s = 0.f;
  for (int i = tid; i < Q; i += 256) s += expf(row[i] - mx);
#pragma unroll
  for (int d = 1; d < 64; d <<= 1) s += __shfl_xor(s, d);
  if ((tid & 63) == 0) red2[tid >> 6] = s;
  __syncthreads();
  s = red2[0] + red2[1] + red2[2] + red2[3];
  if (tid == 0) {
    *(float*)(ws + OFF_AMAX + (size_t)r * 4) = mx;
    *(float*)(ws + OFF_AINV + (size_t)r * 4) = 1.0f / s;
  }
}

__global__ void k_bsoft(const float* __restrict__ Bl, char* __restrict__ ws) {
  const int r = blockIdx.x, l = threadIdx.x;  // 64 threads
  float v = (l < ALPH) ? Bl[(size_t)r * ALPH + l] : -3.0e38f;
  float mx = v;
#pragma unroll
  for (int d = 1; d < 64; d <<= 1) mx = fmaxf(mx, __shfl_xor(mx, d));
  float e = (l < ALPH) ? expf(v - mx) : 0.f;
  float s = e;
#pragma unroll
  for (int d = 1; d < 64; d <<= 1) s += __shfl_xor(s, d);
  if (l < ALPH) *(float*)(ws + OFF_BSOFT + ((size_t)r * ALPH + l) * 4) = e / s;
}

__global__ void k_isoft(const float* __restrict__ il, char* __restrict__ ws) {
  const int tid = threadIdx.x;
  __shared__ float red[4], red2[4];
  float mx = -3.0e38f;
  for (int i = tid; i < Q; i += 256) mx = fmaxf(mx, il[i]);
#pragma unroll
  for (int d = 1; d < 64; d <<= 1) mx = fmaxf(mx, __shfl_xor(mx, d));
  if ((tid & 63) == 0) red[tid >> 6] = mx;
  __syncthreads();
  mx = fmaxf(fmaxf(red[0], red[1]), fmaxf(red[2], red[3]));
  float s = 0.f;
  for (int i = tid; i < Q; i += 256) s += expf(il[i] - mx);
#pragma unroll
  for (int d = 1; d < 64; d <<= 1) s += __shfl_xor(s, d);
  if ((tid & 63) == 0) red2[tid >> 6] = s;
  __syncthreads();
  s = red2[0] + red2[1] + red2[2] + red2[3];
  const float inv = 1.0f / s;
  for (int i = tid; i < Q; i += 256)
    *(float*)(ws + OFF_INIT + (size_t)i * 4) = expf(il[i] - mx) * inv;
}

// Apack[ntile][kc][lane][e] = A[k = kc*32 + (lane>>4)*8 + e][q = ntile*16 + (lane&15)]
__global__ void k_repack(const float* __restrict__ A, char* __restrict__ ws) {
  const int b = blockIdx.x;
  const int nt = b % NTILE, kc = b / NTILE;
  const int lane = threadIdx.x;
  const int q = nt * 16 + (lane & 15);
  const int kb = kc * 32 + (lane >> 4) * 8;
  union { short8 v; unsigned short u[8]; } pk;
#pragma unroll
  for (int e = 0; e < 8; ++e) {
    const int k = kb + e;
    float val = 0.f;
    if (k < Q && q < Q) {
      const float mxk = *(const float*)(ws + OFF_AMAX + (size_t)k * 4);
      const float ivk = *(const float*)(ws + OFF_AINV + (size_t)k * 4);
      val = expf(A[(size_t)k * Q + q] - mxk) * ivk;
    }
    pk.u[e] = (unsigned short)f2bf(val);
  }
  *(short8*)(ws + OFF_APACK + (((size_t)nt * KCH + kc) * 64 + lane) * 16) = pk.v;
}

// ------------------------- main persistent kernel --------------------------

__global__ __launch_bounds__(256, 1) void k_main(const int* __restrict__ xin,
                                                 char* __restrict__ ws,
                                                 float* __restrict__ out) {
  const int bid = blockIdx.x;
  const int c = bid & 15, j = bid >> 4;
  const int tid = threadIdx.x;
  const int lane = tid & 63, w = tid >> 6;
  const int cL = lane & 15, g4 = lane >> 4;
  const int tg = 4 * j + w;              // 16-col tile 0..63 (== wave idx in cluster)
  const bool jx = (j == 15), two = (jx && w == 3);
  const uint64_t wsu = (uint64_t)(uintptr_t)ws;

  __shared__ floatx4 accx[4][5][64];     // 20480 B: [wave][tile-slot][lane]
  __shared__ uint8_t x_lds[MB * TT];     // 8192
  __shared__ float   B_lds[5][16][ALPH]; // 8320
  __shared__ float   init_lds[5][16];    // 320
  __shared__ float   SpW[4][16];         // 256
  __shared__ __attribute__((aligned(16))) float tr_lds[4][16][20];  // 5120 (transpose)

  // ---- stage per-WG constants ----
  for (int idx = tid; idx < MB * TT; idx += 256)
    x_lds[idx] = (uint8_t)xin[(size_t)(c * MB) * TT + idx];
  for (int idx = tid; idx < 5 * 16 * ALPH; idx += 256) {
    const int tl = idx / (16 * ALPH), rem = idx % (16 * ALPH);
    const int cc = rem / ALPH, a = rem % ALPH;
    const int grow = (tl < 4 ? 64 * j + tl * 16 : 1024) + cc;
    B_lds[tl][cc][a] = (grow < Q) ? *(const float*)(ws + OFF_BSOFT + ((size_t)grow * ALPH + a) * 4) : 0.f;
  }
  for (int idx = tid; idx < 5 * 16; idx += 256) {
    const int tl = idx / 16, cc = idx % 16;
    const int grow = (tl < 4 ? 64 * j + tl * 16 : 1024) + cc;
    init_lds[tl][cc] = (grow < Q) ? *(const float*)(ws + OFF_INIT + (size_t)grow * 4) : 0.f;
  }

  // ---- persistent A fragments: af[tt][i] = Apack[4j+tt][kc=4i+w] ----
  short8 af[4][9];
#pragma unroll
  for (int tt = 0; tt < 4; ++tt)
#pragma unroll
    for (int i = 0; i < 9; ++i)
      if (i < 8 || w == 0)
        af[tt][i] = *(const short8*)(ws + OFF_APACK +
                      (((size_t)(4 * j + tt) * KCH + (4 * i + w)) * 64 + lane) * 16);
  short8 afx[9];
  if (jx) {
#pragma unroll
    for (int i = 0; i < 9; ++i)
      if (i < 8 || w == 0)
        afx[i] = *(const short8*)(ws + OFF_APACK +
                      (((size_t)64 * KCH + (4 * i + w)) * 64 + lane) * 16);
  }
  __syncthreads();

  float up0[4], upx[4] = {0.f, 0.f, 0.f, 0.f};
  float uold[4], uxold[4] = {0.f, 0.f, 0.f, 0.f};
  float llacc = 0.f;
  int fpre = 0;                                     // pre-issued poll value (w0)
  const uint64_t fapoll = wsu + OFF_FLAGS + (size_t)(c * 64 + lane) * 4;

  // publish step TCUR: transposed coalesced g-store + per-wave Sp slot,
  // ONE drain, per-wave flag, then (w0) pre-issue next poll load.
#define POST_STEP(TCUR)                                                                   \
  do {                                                                                    \
    const int par_ = (TCUR) & 1;                                                          \
    const uint64_t gb_ = wsu + OFF_GEX + (size_t)(c * 2 + par_) * GIMG;                   \
    /* in-wave 16x16 (m x q) transpose via LDS */                                         \
    _Pragma("unroll") for (int r_ = 0; r_ < 4; ++r_)                                      \
      tr_lds[w][g4 * 4 + r_][cL] = up0[r_];                                               \
    asm volatile("s_waitcnt lgkmcnt(0)" ::: "memory");                                    \
    __builtin_amdgcn_sched_barrier(0);                                                    \
    {                                                                                     \
      const floatx4 tv_ = *(const floatx4*)&tr_lds[w][(lane >> 1) & 15]                   \
                                                   [(lane >> 5) * 8 + (lane & 1) * 4];    \
      intx2 gv_;                                                                          \
      gv_[0] = (int)(f2bf(tv_[0]) | (f2bf(tv_[1]) << 16));                                \
      gv_[1] = (int)(f2bf(tv_[2]) | (f2bf(tv_[3]) << 16));                                \
      asm volatile("global_store_dwordx2 %0, %1, off sc0 sc1" ::                          \
                   "v"(gb_ + (size_t)((tg >> 1) * 1024 + (tg & 1) * 512 + lane * 8)),     \
                   "v"(gv_) : "memory");                                                  \
    }                                                                                     \
    if (two) {                                                                            \
      _Pragma("unroll") for (int r_ = 0; r_ < 4; ++r_)                                    \
        tr_lds[w][g4 * 4 + r_][cL] = upx[r_];                                             \
      asm volatile("s_waitcnt lgkmcnt(0)" ::: "memory");                                  \
      __builtin_amdgcn_sched_barrier(0);                                                  \
      const floatx4 tx_ = *(const floatx4*)&tr_lds[w][(lane >> 1) & 15]                   \
                                                   [(lane >> 5) * 8 + (lane & 1) * 4];    \
      intx2 gx_;                                                                          \
      gx_[0] = (int)(f2bf(tx_[0]) | (f2bf(tx_[1]) << 16));                                \
      gx_[1] = (int)(f2bf(tx_[2]) | (f2bf(tx_[3]) << 16));                                \
      asm volatile("global_store_dwordx2 %0, %1, off sc0 sc1" ::                          \
                   "v"(gb_ + (size_t)(32 * 1024 + lane * 8)), "v"(gx_) : "memory");       \
    }                                                                                     \
    float t0_ = up0[0], t1_ = up0[1], t2_ = up0[2], t3_ = up0[3];                         \
    if (two) { t0_ += upx[0]; t1_ += upx[1]; t2_ += upx[2]; t3_ += upx[3]; }              \
    _Pragma("unroll") for (int d = 1; d < 16; d <<= 1) {                                  \
      t0_ += __shfl_xor(t0_, d); t1_ += __shfl_xor(t1_, d);                               \
      t2_ += __shfl_xor(t2_, d); t3_ += __shfl_xor(t3_, d);                               \
    }                                                                                     \
    if (cL == 0) {                                                                        \
      floatx4 sv_; sv_[0] = t0_; sv_[1] = t1_; sv_[2] = t2_; sv_[3] = t3_;                \
      uint64_t sa_ = wsu + OFF_SP + (size_t)(c * 2 + par_) * 4096 +                       \
                     (size_t)(tg * 64 + g4 * 16);                                         \
      asm volatile("global_store_dwordx4 %0, %1, off sc0 sc1" :: "v"(sa_), "v"(sv_)       \
                   : "memory");                                                           \
    }                                                                                     \
    asm volatile("s_waitcnt vmcnt(0)" ::: "memory");                                      \
    __builtin_amdgcn_sched_barrier(0);                                                    \
    if (lane == 0) {                                                                      \
      int fv_ = (TCUR) + 1;                                                               \
      asm volatile("global_store_dword %0, %1, off sc0 sc1" ::                            \
                   "v"(wsu + OFF_FLAGS + (size_t)(c * 64 + tg) * 4), "v"(fv_) : "memory");\
    }                                                                                     \
    if (w == 0)                                                                           \
      asm volatile("global_load_dword %0, %1, off sc0 sc1"                                \
                   : "=v"(fpre) : "v"(fapoll) : "memory");                                \
  } while (0)

  // wave 0: counted wait on the pre-issued poll (NCNT out-stores in flight),
  // fall into sleep loop on miss; then block sync.
#define WAIT_FLAGS(TGT, NCNT)                                                             \
  do {                                                                                    \
    if (w == 0) {                                                                         \
      asm volatile("s_waitcnt vmcnt(" #NCNT ")" ::: "memory");                            \
      __builtin_amdgcn_sched_barrier(0);                                                  \
      int f_ = fpre;                                                                      \
      while (!__all(f_ >= (TGT))) {                                                       \
        __builtin_amdgcn_s_sleep(2);                                                      \
        asm volatile("global_load_dword %0, %1, off sc0 sc1\n\ts_waitcnt vmcnt(0)"        \
                     : "=v"(f_) : "v"(fapoll) : "memory");                                \
      }                                                                                   \
    }                                                                                     \
    __syncthreads();                                                                      \
  } while (0)

  // ---- step 0: u0 = E0 * init ----
#pragma unroll
  for (int r = 0; r < 4; ++r) {
    const int m = g4 * 4 + r;
    const int xm = x_lds[m * TT + 0];
    up0[r] = B_lds[w][cL][xm] * init_lds[w][cL];
    uold[r] = up0[r];
    if (two) { upx[r] = B_lds[4][cL][xm] * init_lds[4][cL]; uxold[r] = upx[r]; }
  }
  POST_STEP(0);

  for (int t = 1; t < TT; ++t) {
    const int parp = (t - 1) & 1;
    if (t == 1) WAIT_FLAGS(t, 0);   // no out-stores in flight after step 0
    else        WAIT_FLAGS(t, 4);   // 4 out-stores in flight: vmcnt(4) retires poll

    // stage g_{t-1} fragments (regs ARE the MFMA A-operands) + Sp partials
    const uint64_t gb = wsu + OFF_GEX + (size_t)(c * 2 + parp) * GIMG;
    intx4 sg[9], spi;
#pragma unroll
    for (int i = 0; i < 8; ++i)
      asm volatile("global_load_dwordx4 %0, %1, off sc0 sc1"
                   : "=v"(sg[i]) : "v"(gb + (size_t)((i * 256 + tid) * 16)) : "memory");
    if (w == 0)   // wave-uniform: kc=32 chunks
      asm volatile("global_load_dwordx4 %0, %1, off sc0 sc1"
                   : "=v"(sg[8]) : "v"(gb + (size_t)((2048 + lane) * 16)) : "memory");
    asm volatile("global_load_dwordx4 %0, %1, off sc0 sc1"
                 : "=v"(spi)
                 : "v"(wsu + OFF_SP + (size_t)(c * 2 + parp) * 4096 + (size_t)tid * 16)
                 : "memory");
    asm volatile("s_waitcnt vmcnt(1)" ::: "memory");   // all sg arrived; spi in flight
    __builtin_amdgcn_sched_barrier(0);

    // MFMA direct from staged regs: wave w covers kc = 4i+w for its WG's tiles
    floatx4 acc[4] = {{0,0,0,0},{0,0,0,0},{0,0,0,0},{0,0,0,0}};
    floatx4 acx = {0, 0, 0, 0};
#pragma unroll
    for (int i = 0; i < 8; ++i) {
      const short8 gf = __builtin_bit_cast(short8, sg[i]);
#pragma unroll
      for (int tt = 0; tt < 4; ++tt)
        acc[tt] = __builtin_amdgcn_mfma_f32_16x16x32_bf16(gf, af[tt][i], acc[tt], 0, 0, 0);
      if (jx) acx = __builtin_amdgcn_mfma_f32_16x16x32_bf16(gf, afx[i], acx, 0, 0, 0);
    }
    if (w == 0) {  // kc=32 tail
      const short8 gf = __builtin_bit_cast(short8, sg[8]);
#pragma unroll
      for (int tt = 0; tt < 4; ++tt)
        acc[tt] = __builtin_amdgcn_mfma_f32_16x16x32_bf16(gf, af[tt][8], acc[tt], 0, 0, 0);
      if (jx) acx = __builtin_amdgcn_mfma_f32_16x16x32_bf16(gf, afx[8], acx, 0, 0, 0);
    }
    // k-split partials
#pragma unroll
    for (int tt = 0; tt < 4; ++tt) accx[w][tt][lane] = acc[tt];
    if (jx) accx[w][4][lane] = acx;

    // Sp reduce (per-wave partials over the 64 wgi slots)
    asm volatile("s_waitcnt vmcnt(0)" ::: "memory");
    __builtin_amdgcn_sched_barrier(0);
    floatx4 s4 = __builtin_bit_cast(floatx4, spi);
#pragma unroll
    for (int d = 4; d < 64; d <<= 1) {
#pragma unroll
      for (int e = 0; e < 4; ++e) s4[e] += __shfl_xor(s4[e], d);
    }
    if (lane < 4) *(floatx4*)&SpW[w][lane * 4] = s4;
    __syncthreads();  // accx + SpW ready

    // S_{t-1}, cross-wave k-reduce, epilogue
    float invS[4], ot0[4], ot1[4];
    floatx4 rs = accx[0][w][lane] + accx[1][w][lane] + accx[2][w][lane] + accx[3][w][lane];
    float rx[4];
    if (two) {
      floatx4 q = accx[0][4][lane] + accx[1][4][lane] + accx[2][4][lane] + accx[3][4][lane];
#pragma unroll
      for (int r = 0; r < 4; ++r) rx[r] = q[r];
    }
    float llS = 1.f;
    if (lane < 16) llS = SpW[0][lane] + SpW[1][lane] + SpW[2][lane] + SpW[3][lane];
#pragma unroll
    for (int r = 0; r < 4; ++r) {
      const int m = g4 * 4 + r;
      invS[r] = 1.0f / (SpW[0][m] + SpW[1][m] + SpW[2][m] + SpW[3][m]);
      ot0[r] = uold[r] * invS[r];
      if (two) ot1[r] = uxold[r] * invS[r];
      const int xm = x_lds[m * TT + t];
      up0[r] = rs[r] * B_lds[w][cL][xm] * invS[r];
      uold[r] = up0[r];
      if (two) { upx[r] = rx[r] * B_lds[4][cL][xm] * invS[r]; uxold[r] = upx[r]; }
    }

    POST_STEP(t);

    // forward output for t-1 (issued after flag + pre-poll; acks excluded
    // from the next detect by the counted vmcnt(4) wait)
#pragma unroll
    for (int r = 0; r < 4; ++r) {
      const int m = g4 * 4 + r;
      const size_t ob = ((size_t)(c * MB + m) * TT + (t - 1)) * Q;
      __builtin_nontemporal_store(ot0[r], out + ob + tg * 16 + cL);
      if (two && cL < 3)
        __builtin_nontemporal_store(ot1[r], out + ob + 1024 + cL);
    }
    if (j == 0 && w == 0 && lane < 16) llacc += logf(llS);
  }

  // ---- final: S_511, fwd_511, loglik ----
  WAIT_FLAGS(TT, 4);
  {
    const int parp = (TT - 1) & 1;
    intx4 spi;
    asm volatile("global_load_dwordx4 %0, %1, off sc0 sc1\n\ts_waitcnt vmcnt(0)"
                 : "=v"(spi)
                 : "v"(wsu + OFF_SP + (size_t)(c * 2 + parp) * 4096 + (size_t)tid * 16)
                 : "memory");
    __builtin_amdgcn_sched_barrier(0);
    floatx4 s4 = __builtin_bit_cast(floatx4, spi);
#pragma unroll
    for (int d = 4; d < 64; d <<= 1) {
#pragma unroll
      for (int e = 0; e < 4; ++e) s4[e] += __shfl_xor(s4[e], d);
    }
    if (lane < 4) *(floatx4*)&SpW[w][lane * 4] = s4;
    __syncthreads();
    float invS[4];
    float llS = 1.f;
    if (lane < 16) llS = SpW[0][lane] + SpW[1][lane] + SpW[2][lane] + SpW[3][lane];
#pragma unroll
    for (int r = 0; r < 4; ++r) {
      const int m = g4 * 4 + r;
      invS[r] = 1.0f / (SpW[0][m] + SpW[1][m] + SpW[2][m] + SpW[3][m]);
    }
#pragma unroll
    for (int r = 0; r < 4; ++r) {
      const int m = g4 * 4 + r;
      const size_t ob = ((size_t)(c * MB + m) * TT + (TT - 1)) * Q;
      __builtin_nontemporal_store(up0[r] * invS[r], out + ob + tg * 16 + cL);
      if (two && cL < 3)
        __builtin_nontemporal_store(upx[r] * invS[r], out + ob + 1024 + cL);
    }
    if (j == 0 && w == 0 && lane < 16) {
      llacc += logf(llS);
      out[FWDSZ + (size_t)c * MB + lane] = llacc;
    }
  }
}

// ------------------------- launch ------------------------------------------

extern "C" void kernel_launch(void* const* d_in, const int* in_sizes, int n_in,
                              void* d_out, int out_size, void* d_ws, size_t ws_size,
                              hipStream_t stream) {
  const int*   x    = (const int*)d_in[0];
  const float* Alog = (const float*)d_in[1];
  const float* Blog = (const float*)d_in[2];
  const float* ilog = (const float*)d_in[3];
  char*  ws  = (char*)d_ws;
  float* out = (float*)d_out;
  if (ws_size < WS_NEED) return;  // need ~3.4 MB scratch

  hipLaunchKernelGGL(k_zero,   dim3(80),          dim3(256), 0, stream, ws);
  hipLaunchKernelGGL(k_astats, dim3(Q),           dim3(256), 0, stream, Alog, ws);
  hipLaunchKernelGGL(k_bsoft,  dim3(Q),           dim3(64),  0, stream, Blog, ws);
  hipLaunchKernelGGL(k_isoft,  dim3(1),           dim3(256), 0, stream, ilog, ws);
  hipLaunchKernelGGL(k_repack, dim3(NTILE * KCH), dim3(64),  0, stream, Alog, ws);
  hipLaunchKernelGGL(k_main,   dim3(NCL * WPC),   dim3(256), 0, stream, x, ws, out);
}

// Round 13
// 2235.556 us; speedup vs baseline: 1.4417x; 1.4417x over previous
//
#include <hip/hip_runtime.h>
#include <stdint.h>

// ---------------------------------------------------------------------------
// HMM forward: B=256, T=512, Q=1027, ALPHA=26.
// R13 = R10 (runtime-scoped exchange, R7-identical arithmetic) with ONE
// change: cluster mapping c = bid>>4 (16 CONSECUTIVE bids per cluster).
// Rationale: R10's c=bid&15 was XCD-pure only under round-robin dispatch and
// its neutral result suggests the handshake chose the device-scope fallback
// -> dispatch is likely CHUNKED (bids 0..31 -> XCD0, ...). Consecutive-bid
// clusters are pure under chunked dispatch; the proven two-phase visibility
// handshake + device-scope agreement still guarantees correctness under ANY
// placement (impure -> exact R7 sc0 sc1 path).
// ---------------------------------------------------------------------------

#define Q     1027
#define TT    512
#define ALPH  26
#define KCH   33
#define NTILE 65
#define NCHK  (KCH*64)
#define GIMG  (NCHK*16)
#define NCL   16
#define WPC   16
#define MB    16

typedef short  short8  __attribute__((ext_vector_type(8)));
typedef float  floatx4 __attribute__((ext_vector_type(4)));
typedef int    intx4   __attribute__((ext_vector_type(4)));

static constexpr size_t al512(size_t x) { return (x + 511) & ~size_t(511); }
static constexpr size_t OFF_APACK = 0;
static constexpr size_t SZ_APACK  = (size_t)NTILE * KCH * 64 * 16;
static constexpr size_t OFF_BSOFT = al512(OFF_APACK + SZ_APACK);
static constexpr size_t SZ_BSOFT  = (size_t)Q * ALPH * 4;
static constexpr size_t OFF_INIT  = al512(OFF_BSOFT + SZ_BSOFT);
static constexpr size_t OFF_AMAX  = al512(OFF_INIT + Q * 4);
static constexpr size_t OFF_AINV  = al512(OFF_AMAX + Q * 4);
static constexpr size_t OFF_GEX   = al512(OFF_AINV + Q * 4);
static constexpr size_t SZ_GEX    = (size_t)NCL * 2 * GIMG;
static constexpr size_t OFF_SP    = al512(OFF_GEX + SZ_GEX);
static constexpr size_t SZ_SP     = (size_t)NCL * 2 * 64 * MB * 4;
static constexpr size_t OFF_FLAGS = al512(OFF_SP + SZ_SP);
static constexpr size_t SZ_FLAGS  = (size_t)NCL * 64 * 4;
static constexpr size_t OFF_TEST  = al512(OFF_FLAGS + SZ_FLAGS);
static constexpr size_t OFF_TFLG  = al512(OFF_TEST + 4096);
static constexpr size_t OFF_OKF   = al512(OFF_TFLG + 4096);
static constexpr size_t WS_NEED   = OFF_OKF + 4096;
static constexpr size_t FWDSZ     = (size_t)256 * TT * Q;

__device__ __forceinline__ uint32_t f2bf(float f) {
  uint32_t u = __float_as_uint(f);
  return (u + 0x7fffu + ((u >> 16) & 1u)) >> 16;   // RNE
}

// ---- scope-templated memory helpers: DEV -> sc0 sc1 (device), else sc0 (L2)
template <bool DEV> __device__ __forceinline__ void st2(uint64_t a, uint32_t v) {
  if constexpr (DEV) asm volatile("global_store_short %0, %1, off sc0 sc1" :: "v"(a), "v"(v) : "memory");
  else               asm volatile("global_store_short %0, %1, off sc0"     :: "v"(a), "v"(v) : "memory");
}
template <bool DEV> __device__ __forceinline__ void st4(uint64_t a, int v) {
  if constexpr (DEV) asm volatile("global_store_dword %0, %1, off sc0 sc1" :: "v"(a), "v"(v) : "memory");
  else               asm volatile("global_store_dword %0, %1, off sc0"     :: "v"(a), "v"(v) : "memory");
}
template <bool DEV> __device__ __forceinline__ void st16(uint64_t a, floatx4 v) {
  if constexpr (DEV) asm volatile("global_store_dwordx4 %0, %1, off sc0 sc1" :: "v"(a), "v"(v) : "memory");
  else               asm volatile("global_store_dwordx4 %0, %1, off sc0"     :: "v"(a), "v"(v) : "memory");
}
template <bool DEV> __device__ __forceinline__ intx4 ld16(uint64_t a) {
  intx4 r;
  if constexpr (DEV) asm volatile("global_load_dwordx4 %0, %1, off sc0 sc1" : "=v"(r) : "v"(a) : "memory");
  else               asm volatile("global_load_dwordx4 %0, %1, off sc0"     : "=v"(r) : "v"(a) : "memory");
  return r;
}
template <bool DEV> __device__ __forceinline__ int ld4w(uint64_t a) {
  int r;
  if constexpr (DEV) asm volatile("global_load_dword %0, %1, off sc0 sc1\n\ts_waitcnt vmcnt(0)" : "=v"(r) : "v"(a) : "memory");
  else               asm volatile("global_load_dword %0, %1, off sc0\n\ts_waitcnt vmcnt(0)"     : "=v"(r) : "v"(a) : "memory");
  return r;
}

// ------------------------- prep kernels ------------------------------------

__global__ void k_zero(char* __restrict__ ws) {
  const size_t n = (WS_NEED - OFF_GEX) / 16;
  intx4* p = (intx4*)(ws + OFF_GEX);
  for (size_t i = (size_t)blockIdx.x * 256 + threadIdx.x; i < n; i += (size_t)80 * 256)
    p[i] = intx4{0, 0, 0, 0};
}

__global__ void k_astats(const float* __restrict__ A, char* __restrict__ ws) {
  const int r = blockIdx.x, tid = threadIdx.x;
  const float* row = A + (size_t)r * Q;
  __shared__ float red[4], red2[4];
  float mx = -3.0e38f;
  for (int i = tid; i < Q; i += 256) mx = fmaxf(mx, row[i]);
#pragma unroll
  for (int d = 1; d < 64; d <<= 1) mx = fmaxf(mx, __shfl_xor(mx, d));
  if ((tid & 63) == 0) red[tid >> 6] = mx;
  __syncthreads();
  mx = fmaxf(fmaxf(red[0], red[1]), fmaxf(red[2], red[3]));
  float s = 0.f;
  for (int i = tid; i < Q; i += 256) s += expf(row[i] - mx);
#pragma unroll
  for (int d = 1; d < 64; d <<= 1) s += __shfl_xor(s, d);
  if ((tid & 63) == 0) red2[tid >> 6] = s;
  __syncthreads();
  s = red2[0] + red2[1] + red2[2] + red2[3];
  if (tid == 0) {
    *(float*)(ws + OFF_AMAX + (size_t)r * 4) = mx;
    *(float*)(ws + OFF_AINV + (size_t)r * 4) = 1.0f / s;
  }
}

__global__ void k_bsoft(const float* __restrict__ Bl, char* __restrict__ ws) {
  const int r = blockIdx.x, l = threadIdx.x;
  float v = (l < ALPH) ? Bl[(size_t)r * ALPH + l] : -3.0e38f;
  float mx = v;
#pragma unroll
  for (int d = 1; d < 64; d <<= 1) mx = fmaxf(mx, __shfl_xor(mx, d));
  float e = (l < ALPH) ? expf(v - mx) : 0.f;
  float s = e;
#pragma unroll
  for (int d = 1; d < 64; d <<= 1) s += __shfl_xor(s, d);
  if (l < ALPH) *(float*)(ws + OFF_BSOFT + ((size_t)r * ALPH + l) * 4) = e / s;
}

__global__ void k_isoft(const float* __restrict__ il, char* __restrict__ ws) {
  const int tid = threadIdx.x;
  __shared__ float red[4], red2[4];
  float mx = -3.0e38f;
  for (int i = tid; i < Q; i += 256) mx = fmaxf(mx, il[i]);
#pragma unroll
  for (int d = 1; d < 64; d <<= 1) mx = fmaxf(mx, __shfl_xor(mx, d));
  if ((tid & 63) == 0) red[tid >> 6] = mx;
  __syncthreads();
  mx = fmaxf(fmaxf(red[0], red[1]), fmaxf(red[2], red[3]));
  float s = 0.f;
  for (int i = tid; i < Q; i += 256) s += expf(il[i] - mx);
#pragma unroll
  for (int d = 1; d < 64; d <<= 1) s += __shfl_xor(s, d);
  if ((tid & 63) == 0) red2[tid >> 6] = s;
  __syncthreads();
  s = red2[0] + red2[1] + red2[2] + red2[3];
  const float inv = 1.0f / s;
  for (int i = tid; i < Q; i += 256)
    *(float*)(ws + OFF_INIT + (size_t)i * 4) = expf(il[i] - mx) * inv;
}

__global__ void k_repack(const float* __restrict__ A, char* __restrict__ ws) {
  const int b = blockIdx.x;
  const int nt = b % NTILE, kc = b / NTILE;
  const int lane = threadIdx.x;
  const int q = nt * 16 + (lane & 15);
  const int kb = kc * 32 + (lane >> 4) * 8;
  union { short8 v; unsigned short u[8]; } pk;
#pragma unroll
  for (int e = 0; e < 8; ++e) {
    const int k = kb + e;
    float val = 0.f;
    if (k < Q && q < Q) {
      const float mxk = *(const float*)(ws + OFF_AMAX + (size_t)k * 4);
      const float ivk = *(const float*)(ws + OFF_AINV + (size_t)k * 4);
      val = expf(A[(size_t)k * Q + q] - mxk) * ivk;
    }
    pk.u[e] = (unsigned short)f2bf(val);
  }
  *(short8*)(ws + OFF_APACK + (((size_t)nt * KCH + kc) * 64 + lane) * 16) = pk.v;
}

// ------------------------- templated main loop -----------------------------

template <bool DEV>
__device__ __forceinline__ void hmm_run(char* __restrict__ ws, float* __restrict__ out,
                                        int c, int j,
                                        uint8_t (&x_lds)[MB * TT],
                                        float (&B_lds)[5][16][ALPH],
                                        float (&init_lds)[5][16],
                                        floatx4 (&accx)[4][5][64],
                                        float (&SpW)[4][16]) {
  const int tid = threadIdx.x;
  const int lane = tid & 63, w = tid >> 6;
  const int cL = lane & 15, g4 = lane >> 4;
  const int tg = 4 * j + w;
  const bool jx = (j == 15), two = (jx && w == 3);
  const uint64_t wsu = (uint64_t)(uintptr_t)ws;

  short8 af[4][9];
#pragma unroll
  for (int tt = 0; tt < 4; ++tt)
#pragma unroll
    for (int i = 0; i < 9; ++i)
      if (i < 8 || w == 0)
        af[tt][i] = *(const short8*)(ws + OFF_APACK +
                      (((size_t)(4 * j + tt) * KCH + (4 * i + w)) * 64 + lane) * 16);
  short8 afx[9];
  if (jx) {
#pragma unroll
    for (int i = 0; i < 9; ++i)
      if (i < 8 || w == 0)
        afx[i] = *(const short8*)(ws + OFF_APACK +
                      (((size_t)64 * KCH + (4 * i + w)) * 64 + lane) * 16);
  }
  __syncthreads();

  float up0[4], upx[4] = {0.f, 0.f, 0.f, 0.f};
  float uold[4], uxold[4] = {0.f, 0.f, 0.f, 0.f};
  float llacc = 0.f;

#define POST_STEP(TCUR)                                                                   \
  do {                                                                                    \
    const int par_ = (TCUR) & 1;                                                          \
    const uint64_t gb_ = wsu + OFF_GEX + (size_t)(c * 2 + par_) * GIMG;                   \
    const uint64_t b0_ = gb_ + (size_t)((tg >> 1) * 1024 + ((tg & 1) * 2 + (cL >> 3)) * 256 \
                         + g4 * 64 + (cL & 7) * 2);                                       \
    float t0_ = up0[0], t1_ = up0[1], t2_ = up0[2], t3_ = up0[3];                         \
    _Pragma("unroll") for (int r_ = 0; r_ < 4; ++r_)                                      \
      st2<DEV>(b0_ + (size_t)(r_ * 16), f2bf(up0[r_]));                                   \
    if (two) {                                                                            \
      const uint64_t bx_ = gb_ + (size_t)(32 * 1024 + (cL >> 3) * 256 + g4 * 64 + (cL & 7) * 2); \
      _Pragma("unroll") for (int r_ = 0; r_ < 4; ++r_)                                    \
        st2<DEV>(bx_ + (size_t)(r_ * 16), f2bf(upx[r_]));                                 \
      t0_ += upx[0]; t1_ += upx[1]; t2_ += upx[2]; t3_ += upx[3];                         \
    }                                                                                     \
    _Pragma("unroll") for (int d = 1; d < 16; d <<= 1) {                                  \
      t0_ += __shfl_xor(t0_, d); t1_ += __shfl_xor(t1_, d);                               \
      t2_ += __shfl_xor(t2_, d); t3_ += __shfl_xor(t3_, d);                               \
    }                                                                                     \
    if (cL == 0) {                                                                        \
      floatx4 sv_; sv_[0] = t0_; sv_[1] = t1_; sv_[2] = t2_; sv_[3] = t3_;                \
      st16<DEV>(wsu + OFF_SP + (size_t)(c * 2 + par_) * 4096 + (size_t)(tg * 64 + g4 * 16), sv_); \
    }                                                                                     \
    asm volatile("s_waitcnt vmcnt(0)" ::: "memory");                                      \
    __builtin_amdgcn_sched_barrier(0);                                                    \
    if (lane == 0)                                                                        \
      st4<DEV>(wsu + OFF_FLAGS + (size_t)(c * 64 + tg) * 4, (TCUR) + 1);                  \
  } while (0)

#define WAIT_FLAGS(TGT)                                                                   \
  do {                                                                                    \
    if (w == 0) {                                                                         \
      const uint64_t fa_ = wsu + OFF_FLAGS + (size_t)(c * 64 + lane) * 4;                 \
      for (;;) {                                                                          \
        int f_ = ld4w<DEV>(fa_);                                                          \
        if (__all(f_ >= (TGT))) break;                                                    \
        if constexpr (DEV) __builtin_amdgcn_s_sleep(2);                                   \
        else               __builtin_amdgcn_s_sleep(1);                                   \
      }                                                                                   \
    }                                                                                     \
    __syncthreads();                                                                      \
  } while (0)

  // ---- step 0 ----
#pragma unroll
  for (int r = 0; r < 4; ++r) {
    const int m = g4 * 4 + r;
    const int xm = x_lds[m * TT + 0];
    up0[r] = B_lds[w][cL][xm] * init_lds[w][cL];
    uold[r] = up0[r];
    if (two) { upx[r] = B_lds[4][cL][xm] * init_lds[4][cL]; uxold[r] = upx[r]; }
  }
  POST_STEP(0);

  for (int t = 1; t < TT; ++t) {
    const int parp = (t - 1) & 1;
    WAIT_FLAGS(t);

    const uint64_t gb = wsu + OFF_GEX + (size_t)(c * 2 + parp) * GIMG;
    intx4 sg[9], spi;
#pragma unroll
    for (int i = 0; i < 8; ++i)
      sg[i] = ld16<DEV>(gb + (size_t)((i * 256 + tid) * 16));
    if (w == 0)
      sg[8] = ld16<DEV>(gb + (size_t)((2048 + lane) * 16));
    spi = ld16<DEV>(wsu + OFF_SP + (size_t)(c * 2 + parp) * 4096 + (size_t)tid * 16);
    asm volatile("s_waitcnt vmcnt(1)" ::: "memory");
    __builtin_amdgcn_sched_barrier(0);

    floatx4 acc[4] = {{0,0,0,0},{0,0,0,0},{0,0,0,0},{0,0,0,0}};
    floatx4 acx = {0, 0, 0, 0};
#pragma unroll
    for (int i = 0; i < 8; ++i) {
      const short8 gf = __builtin_bit_cast(short8, sg[i]);
#pragma unroll
      for (int tt = 0; tt < 4; ++tt)
        acc[tt] = __builtin_amdgcn_mfma_f32_16x16x32_bf16(gf, af[tt][i], acc[tt], 0, 0, 0);
      if (jx) acx = __builtin_amdgcn_mfma_f32_16x16x32_bf16(gf, afx[i], acx, 0, 0, 0);
    }
    if (w == 0) {
      const short8 gf = __builtin_bit_cast(short8, sg[8]);
#pragma unroll
      for (int tt = 0; tt < 4; ++tt)
        acc[tt] = __builtin_amdgcn_mfma_f32_16x16x32_bf16(gf, af[tt][8], acc[tt], 0, 0, 0);
      if (jx) acx = __builtin_amdgcn_mfma_f32_16x16x32_bf16(gf, afx[8], acx, 0, 0, 0);
    }
#pragma unroll
    for (int tt = 0; tt < 4; ++tt) accx[w][tt][lane] = acc[tt];
    if (jx) accx[w][4][lane] = acx;

    asm volatile("s_waitcnt vmcnt(0)" ::: "memory");
    __builtin_amdgcn_sched_barrier(0);
    floatx4 s4 = __builtin_bit_cast(floatx4, spi);
#pragma unroll
    for (int d = 4; d < 64; d <<= 1) {
#pragma unroll
      for (int e = 0; e < 4; ++e) s4[e] += __shfl_xor(s4[e], d);
    }
    if (lane < 4) *(floatx4*)&SpW[w][lane * 4] = s4;
    __syncthreads();

    float invS[4], ot0[4], ot1[4];
    floatx4 rs = accx[0][w][lane] + accx[1][w][lane] + accx[2][w][lane] + accx[3][w][lane];
    float rx[4];
    if (two) {
      floatx4 q = accx[0][4][lane] + accx[1][4][lane] + accx[2][4][lane] + accx[3][4][lane];
#pragma unroll
      for (int r = 0; r < 4; ++r) rx[r] = q[r];
    }
    float llS = 1.f;
    if (lane < 16) llS = SpW[0][lane] + SpW[1][lane] + SpW[2][lane] + SpW[3][lane];
#pragma unroll
    for (int r = 0; r < 4; ++r) {
      const int m = g4 * 4 + r;
      invS[r] = 1.0f / (SpW[0][m] + SpW[1][m] + SpW[2][m] + SpW[3][m]);
      ot0[r] = uold[r] * invS[r];
      if (two) ot1[r] = uxold[r] * invS[r];
      const int xm = x_lds[m * TT + t];
      up0[r] = rs[r] * B_lds[w][cL][xm] * invS[r];
      uold[r] = up0[r];
      if (two) { upx[r] = rx[r] * B_lds[4][cL][xm] * invS[r]; uxold[r] = upx[r]; }
    }

    POST_STEP(t);

#pragma unroll
    for (int r = 0; r < 4; ++r) {
      const int m = g4 * 4 + r;
      const size_t ob = ((size_t)(c * MB + m) * TT + (t - 1)) * Q;
      __builtin_nontemporal_store(ot0[r], out + ob + tg * 16 + cL);
      if (two && cL < 3)
        __builtin_nontemporal_store(ot1[r], out + ob + 1024 + cL);
    }
    if (j == 0 && w == 0 && lane < 16) llacc += logf(llS);
  }

  // ---- final ----
  WAIT_FLAGS(TT);
  {
    const int parp = (TT - 1) & 1;
    intx4 spi = ld16<DEV>(wsu + OFF_SP + (size_t)(c * 2 + parp) * 4096 + (size_t)tid * 16);
    asm volatile("s_waitcnt vmcnt(0)" ::: "memory");
    __builtin_amdgcn_sched_barrier(0);
    floatx4 s4 = __builtin_bit_cast(floatx4, spi);
#pragma unroll
    for (int d = 4; d < 64; d <<= 1) {
#pragma unroll
      for (int e = 0; e < 4; ++e) s4[e] += __shfl_xor(s4[e], d);
    }
    if (lane < 4) *(floatx4*)&SpW[w][lane * 4] = s4;
    __syncthreads();
    float invS[4];
    float llS = 1.f;
    if (lane < 16) llS = SpW[0][lane] + SpW[1][lane] + SpW[2][lane] + SpW[3][lane];
#pragma unroll
    for (int r = 0; r < 4; ++r) {
      const int m = g4 * 4 + r;
      invS[r] = 1.0f / (SpW[0][m] + SpW[1][m] + SpW[2][m] + SpW[3][m]);
    }
#pragma unroll
    for (int r = 0; r < 4; ++r) {
      const int m = g4 * 4 + r;
      const size_t ob = ((size_t)(c * MB + m) * TT + (TT - 1)) * Q;
      __builtin_nontemporal_store(up0[r] * invS[r], out + ob + tg * 16 + cL);
      if (two && cL < 3)
        __builtin_nontemporal_store(upx[r] * invS[r], out + ob + 1024 + cL);
    }
    if (j == 0 && w == 0 && lane < 16) {
      llacc += logf(llS);
      out[FWDSZ + (size_t)c * MB + lane] = llacc;
    }
  }
#undef POST_STEP
#undef WAIT_FLAGS
}

// ------------------------- main kernel -------------------------------------

__global__ __launch_bounds__(256, 1) void k_main(const int* __restrict__ xin,
                                                 char* __restrict__ ws,
                                                 float* __restrict__ out) {
  const int bid = blockIdx.x;
  const int c = bid >> 4, j = bid & 15;   // <<< R13: consecutive-bid clusters
  const int tid = threadIdx.x;
  const int lane = tid & 63, w = tid >> 6;
  const int tg = 4 * j + w;
  const uint64_t wsu = (uint64_t)(uintptr_t)ws;

  __shared__ floatx4 accx[4][5][64];
  __shared__ uint8_t x_lds[MB * TT];
  __shared__ float   B_lds[5][16][ALPH];
  __shared__ float   init_lds[5][16];
  __shared__ float   SpW[4][16];

  // ---- stage per-WG constants ----
  for (int idx = tid; idx < MB * TT; idx += 256)
    x_lds[idx] = (uint8_t)xin[(size_t)(c * MB) * TT + idx];
  for (int idx = tid; idx < 5 * 16 * ALPH; idx += 256) {
    const int tl = idx / (16 * ALPH), rem = idx % (16 * ALPH);
    const int cc = rem / ALPH, a = rem % ALPH;
    const int grow = (tl < 4 ? 64 * j + tl * 16 : 1024) + cc;
    B_lds[tl][cc][a] = (grow < Q) ? *(const float*)(ws + OFF_BSOFT + ((size_t)grow * ALPH + a) * 4) : 0.f;
  }
  for (int idx = tid; idx < 5 * 16; idx += 256) {
    const int tl = idx / 16, cc = idx % 16;
    const int grow = (tl < 4 ? 64 * j + tl * 16 : 1024) + cc;
    init_lds[tl][cc] = (grow < Q) ? *(const float*)(ws + OFF_INIT + (size_t)grow * 4) : 0.f;
  }

  // ---- two-phase same-L2 visibility handshake (decides scope per cluster) ----
  bool pure;
  {
    const uint64_t ta  = wsu + OFF_TEST + (size_t)(c * 64 + tg) * 4;
    const uint64_t tfa = wsu + OFF_TFLG + (size_t)(c * 64 + tg) * 4;
    const uint64_t pta = wsu + OFF_TEST + (size_t)(c * 64 + lane) * 4;
    const uint64_t pfa = wsu + OFF_TFLG + (size_t)(c * 64 + lane) * 4;
    bool ok = true;
    int gate = 0;
#pragma unroll 1
    for (int ph = 0; ph < 2; ++ph) {
      const int magic = 0x5A100000 + ph * 0x10000;
      if (lane == 0) {
        asm volatile("global_store_dword %0, %1, off sc0" :: "v"(ta), "v"(magic + tg) : "memory");
        asm volatile("s_waitcnt vmcnt(0)" ::: "memory");
        st4<true>(tfa, ++gate);
      } else { ++gate; }
      for (;;) {
        int fv = ld4w<true>(pfa);
        if (__all(fv >= gate)) break;
        __builtin_amdgcn_s_sleep(2);
      }
      int tv;
      asm volatile("global_load_dword %0, %1, off sc0\n\ts_waitcnt vmcnt(0)" : "=v"(tv) : "v"(pta) : "memory");
      ok = ok && __all(tv == magic + (int)lane);
      if (lane == 0) st4<true>(tfa, ++gate); else ++gate;
      for (;;) {
        int fv = ld4w<true>(pfa);
        if (__all(fv >= gate)) break;
        __builtin_amdgcn_s_sleep(2);
      }
    }
    if (lane == 0) st4<true>(wsu + OFF_OKF + (size_t)(c * 64 + tg) * 4, ok ? 2 : 1);
    int av;
    for (;;) {
      av = ld4w<true>(wsu + OFF_OKF + (size_t)(c * 64 + lane) * 4);
      if (__all(av != 0)) break;
      __builtin_amdgcn_s_sleep(2);
    }
    pure = __all(av == 2);
  }

  if (pure) hmm_run<false>(ws, out, c, j, x_lds, B_lds, init_lds, accx, SpW);
  else      hmm_run<true>(ws, out, c, j, x_lds, B_lds, init_lds, accx, SpW);
}

// ------------------------- launch ------------------------------------------

extern "C" void kernel_launch(void* const* d_in, const int* in_sizes, int n_in,
                              void* d_out, int out_size, void* d_ws, size_t ws_size,
                              hipStream_t stream) {
  const int*   x    = (const int*)d_in[0];
  const float* Alog = (const float*)d_in[1];
  const float* Blog = (const float*)d_in[2];
  const float* ilog = (const float*)d_in[3];
  char*  ws  = (char*)d_ws;
  float* out = (float*)d_out;
  if (ws_size < WS_NEED) return;  // need ~3.4 MB scratch

  hipLaunchKernelGGL(k_zero,   dim3(80),          dim3(256), 0, stream, ws);
  hipLaunchKernelGGL(k_astats, dim3(Q),           dim3(256), 0, stream, Alog, ws);
  hipLaunchKernelGGL(k_bsoft,  dim3(Q),           dim3(64),  0, stream, Blog, ws);
  hipLaunchKernelGGL(k_isoft,  dim3(1),           dim3(256), 0, stream, ilog, ws);
  hipLaunchKernelGGL(k_repack, dim3(NTILE * KCH), dim3(64),  0, stream, Alog, ws);
  hipLaunchKernelGGL(k_main,   dim3(NCL * WPC),   dim3(256), 0, stream, x, ws, out);
}